// Round 1
// baseline (2981.185 us; speedup 1.0000x reference)
//
#include <hip/hip_runtime.h>

#define D 128

// ---------------- edge dtype detection + repack ----------------
// If edge_index arrived as int64, every odd int32 word of the first 2E words
// (the src row viewed as (lo,hi) pairs) is 0. With genuine int32 data those
// words are random node ids -> astronomically unlikely to all be zero.
__global__ __launch_bounds__(256) void detect_mode(const int* __restrict__ e, int* __restrict__ mode, int E) {
    int found = 0;
    for (int p = blockIdx.x * 256 + threadIdx.x; p < E; p += gridDim.x * 256)
        if (e[2 * p + 1] != 0) found = 1;
    if (found) atomicOr(mode, 1);   // 1 => int32, 0 => int64
}

__global__ __launch_bounds__(256) void repack_edges(const void* __restrict__ eraw, const int* __restrict__ mode,
                                                    int* __restrict__ out, int n2) {
    int i = blockIdx.x * 256 + threadIdx.x;
    if (i >= n2) return;
    int m = *mode;
    out[i] = m ? ((const int*)eraw)[i] : (int)((const long long*)eraw)[i];
}

// ---------------- degree / normalization ----------------
__global__ __launch_bounds__(256) void compute_deg(const int* __restrict__ dst, unsigned* __restrict__ deg, int E) {
    int i = blockIdx.x * 256 + threadIdx.x;
    if (i < E) atomicAdd(&deg[dst[i]], 1u);
}

__global__ __launch_bounds__(256) void compute_dinv(const unsigned* __restrict__ deg, float* __restrict__ dinv, int N) {
    int i = blockIdx.x * 256 + threadIdx.x;
    if (i < N) dinv[i] = 1.0f / sqrtf((float)(deg[i] + 1u));   // +1 self-loop, so >= 1
}

// ---------------- GEMM: C[N,128] = A[N,128] @ W[128,128] (+bias) ----------------
// 32-row tile, W staged in two K-halves (48KB LDS total -> 3 blocks/CU).
template<bool BIAS>
__global__ __launch_bounds__(256) void gemm128(const float* __restrict__ A, const float* __restrict__ W,
                                               const float* __restrict__ bias, float* __restrict__ C, int N) {
    __shared__ float Ws[64][D];    // 32KB: one K-half of W
    __shared__ float As[32][D];    // 16KB
    int tid = threadIdx.x;
    int row0 = blockIdx.x * 32;
    for (int i = tid; i < 32 * 32; i += 256) {
        int r = i >> 5, c4 = i & 31;
        float4 v = make_float4(0.f, 0.f, 0.f, 0.f);
        if (row0 + r < N) v = *((const float4*)(A + (size_t)(row0 + r) * D) + c4);
        *((float4*)&As[r][0] + c4) = v;
    }
    int ct = tid & 31;   // cols 4*ct .. 4*ct+3
    int rt = tid >> 5;   // rows rt*4 .. rt*4+3
    float acc[4][4] = {{0.f}};
    for (int kh = 0; kh < 2; kh++) {
        __syncthreads();
        for (int i = tid; i < 64 * 32; i += 256)
            ((float4*)Ws)[i] = ((const float4*)(W + kh * 64 * D))[i];
        __syncthreads();
        #pragma unroll
        for (int k = 0; k < 64; k += 4) {
            float4 w0 = *(const float4*)&Ws[k + 0][4 * ct];
            float4 w1 = *(const float4*)&Ws[k + 1][4 * ct];
            float4 w2 = *(const float4*)&Ws[k + 2][4 * ct];
            float4 w3 = *(const float4*)&Ws[k + 3][4 * ct];
            #pragma unroll
            for (int r = 0; r < 4; r++) {
                float4 av = *(const float4*)&As[rt * 4 + r][kh * 64 + k];
                acc[r][0] += av.x * w0.x + av.y * w1.x + av.z * w2.x + av.w * w3.x;
                acc[r][1] += av.x * w0.y + av.y * w1.y + av.z * w2.y + av.w * w3.y;
                acc[r][2] += av.x * w0.z + av.y * w1.z + av.z * w2.z + av.w * w3.z;
                acc[r][3] += av.x * w0.w + av.y * w1.w + av.z * w2.w + av.w * w3.w;
            }
        }
    }
    #pragma unroll
    for (int r = 0; r < 4; r++) {
        int row = row0 + rt * 4 + r;
        if (row < N) {
            float4 o = make_float4(acc[r][0], acc[r][1], acc[r][2], acc[r][3]);
            if (BIAS) {
                float4 b = *((const float4*)bias + ct);
                o.x += b.x; o.y += b.y; o.z += b.z; o.w += b.w;
            }
            *((float4*)(C + (size_t)row * D) + ct) = o;
        }
    }
}

// ---------------- post GEMM: C[N,40] = A[N,128] @ W[128,40] + bias ----------------
__global__ __launch_bounds__(256) void gemm_post(const float* __restrict__ A, const float* __restrict__ W,
                                                 const float* __restrict__ bias, float* __restrict__ C, int N) {
    __shared__ float WsT[40][132];   // transposed, padded (bank-conflict-free float4 reads)
    __shared__ float As[32][132];
    int tid = threadIdx.x;
    for (int i = tid; i < 128 * 40; i += 256) {
        int k = i / 40, c = i % 40;
        WsT[c][k] = W[i];
    }
    int row0 = blockIdx.x * 32;
    for (int i = tid; i < 32 * 32; i += 256) {
        int r = i >> 5, c4 = i & 31;
        float4 v = make_float4(0.f, 0.f, 0.f, 0.f);
        if (row0 + r < N) v = *((const float4*)(A + (size_t)(row0 + r) * D) + c4);
        *((float4*)&As[r][0] + c4) = v;
    }
    __syncthreads();
    int r = tid >> 3;    // 32 rows
    int cg = tid & 7;    // 8 col groups x 5 cols
    float acc[5] = {0.f, 0.f, 0.f, 0.f, 0.f};
    #pragma unroll
    for (int k = 0; k < 128; k += 4) {
        float4 av = *(const float4*)&As[r][k];
        #pragma unroll
        for (int j = 0; j < 5; j++) {
            float4 wv = *(const float4*)&WsT[cg * 5 + j][k];
            acc[j] += av.x * wv.x + av.y * wv.y + av.z * wv.z + av.w * wv.w;
        }
    }
    int row = row0 + r;
    if (row < N) {
        #pragma unroll
        for (int j = 0; j < 5; j++) {
            int c = cg * 5 + j;
            C[(size_t)row * 40 + c] = acc[j] + bias[c];
        }
    }
}

// ---------------- message passing: atomic scatter-add ----------------
// 32 lanes per edge, float4 per lane: gather t[src]*norm, atomicAdd into acc[dst].
__global__ __launch_bounds__(256) void scatter_edges(const int* __restrict__ src, const int* __restrict__ dst,
                                                     const float* __restrict__ dinv, const float* __restrict__ t,
                                                     float* __restrict__ acc, int E) {
    int idx = blockIdx.x * 256 + threadIdx.x;
    int e = idx >> 5;
    if (e >= E) return;
    int lane = idx & 31;
    int s = src[e], d = dst[e];
    float nrm = dinv[s] * dinv[d];
    float4 v = *((const float4*)(t + (size_t)s * D) + lane);
    float* a = acc + (size_t)d * D + lane * 4;
    atomicAdd(a + 0, v.x * nrm);
    atomicAdd(a + 1, v.y * nrm);
    atomicAdd(a + 2, v.z * nrm);
    atomicAdd(a + 3, v.w * nrm);
}

// out = relu(acc + t*dinv^2 + bias)  (adds the self-loop message)
__global__ __launch_bounds__(256) void finalize_relu(const float* __restrict__ acc, const float* __restrict__ t,
                                                     const float* __restrict__ dinv, const float* __restrict__ bias,
                                                     float* __restrict__ out, int N) {
    int i = blockIdx.x * 256 + threadIdx.x;
    if (i >= N * 32) return;
    int n = i >> 5, c4 = i & 31;
    float di = dinv[n];
    float sn = di * di;
    float4 a = ((const float4*)acc)[i];
    float4 tv = ((const float4*)t)[i];
    float4 b = ((const float4*)bias)[c4];
    float4 r;
    r.x = fmaxf(fmaf(tv.x, sn, a.x) + b.x, 0.f);
    r.y = fmaxf(fmaf(tv.y, sn, a.y) + b.y, 0.f);
    r.z = fmaxf(fmaf(tv.z, sn, a.z) + b.z, 0.f);
    r.w = fmaxf(fmaf(tv.w, sn, a.w) + b.w, 0.f);
    ((float4*)out)[i] = r;
}

extern "C" void kernel_launch(void* const* d_in, const int* in_sizes, int n_in,
                              void* d_out, int out_size, void* d_ws, size_t ws_size,
                              hipStream_t stream) {
    const float* x      = (const float*)d_in[0];
    const void*  edges  = d_in[1];
    const float* W_pre  = (const float*)d_in[2];
    const float* b_pre  = (const float*)d_in[3];
    const float* W1     = (const float*)d_in[4];
    const float* b1     = (const float*)d_in[5];
    const float* W2     = (const float*)d_in[6];
    const float* b2     = (const float*)d_in[7];
    const float* W_post = (const float*)d_in[8];
    const float* b_post = (const float*)d_in[9];
    float* out = (float*)d_out;

    const int N = in_sizes[0] / D;      // 50000
    const int E = in_sizes[1] / 2;      // 800000

    // workspace layout
    char* ws = (char*)d_ws;
    size_t off = 0;
    auto alloc = [&](size_t bytes) { void* p = ws + off; off += (bytes + 255) & ~(size_t)255; return p; };
    float*    bufA   = (float*)alloc((size_t)N * D * 4);   // current h
    float*    bufB   = (float*)alloc((size_t)N * D * 4);   // t = h @ W
    float*    bufC   = (float*)alloc((size_t)N * D * 4);   // scatter accumulator
    float*    dinv   = (float*)alloc((size_t)N * 4);
    unsigned* deg    = (unsigned*)alloc((size_t)N * 4);
    int*      mode   = (int*)alloc(256);
    int*      srcdst = (int*)alloc((size_t)2 * E * 4);
    int* src = srcdst;
    int* dst = srcdst + E;

    const int nGemmBlocks = (N + 31) / 32;

    // graph prep (once per call; shared by both convs)
    hipMemsetAsync(deg, 0, (size_t)N * 4, stream);
    hipMemsetAsync(mode, 0, 4, stream);
    detect_mode<<<512, 256, 0, stream>>>((const int*)edges, mode, E);
    repack_edges<<<(2 * E + 255) / 256, 256, 0, stream>>>(edges, mode, srcdst, 2 * E);
    compute_deg<<<(E + 255) / 256, 256, 0, stream>>>(dst, deg, E);
    compute_dinv<<<(N + 255) / 256, 256, 0, stream>>>(deg, dinv, N);

    // pre MLP: bufA = x @ W_pre + b_pre
    gemm128<true><<<nGemmBlocks, 256, 0, stream>>>(x, W_pre, b_pre, bufA, N);

    // conv1
    gemm128<false><<<nGemmBlocks, 256, 0, stream>>>(bufA, W1, nullptr, bufB, N);
    hipMemsetAsync(bufC, 0, (size_t)N * D * 4, stream);
    scatter_edges<<<E / 8, 256, 0, stream>>>(src, dst, dinv, bufB, bufC, E);
    finalize_relu<<<(N * 32 + 255) / 256, 256, 0, stream>>>(bufC, bufB, dinv, b1, bufA, N);

    // conv2
    gemm128<false><<<nGemmBlocks, 256, 0, stream>>>(bufA, W2, nullptr, bufB, N);
    hipMemsetAsync(bufC, 0, (size_t)N * D * 4, stream);
    scatter_edges<<<E / 8, 256, 0, stream>>>(src, dst, dinv, bufB, bufC, E);
    finalize_relu<<<(N * 32 + 255) / 256, 256, 0, stream>>>(bufC, bufB, dinv, b2, bufA, N);

    // post MLP -> d_out
    gemm_post<<<nGemmBlocks, 256, 0, stream>>>(bufA, W_post, b_post, out, N);
}

// Round 2
// 438.327 us; speedup vs baseline: 6.8013x; 6.8013x over previous
//
#include <hip/hip_runtime.h>

#define D 128

// ---------------- edge dtype detection + repack ----------------
__global__ __launch_bounds__(256) void detect_mode(const int* __restrict__ e, int* __restrict__ mode, int E) {
    int found = 0;
    for (int p = blockIdx.x * 256 + threadIdx.x; p < E; p += gridDim.x * 256)
        if (e[2 * p + 1] != 0) found = 1;
    if (found) atomicOr(mode, 1);   // 1 => int32, 0 => int64
}

__global__ __launch_bounds__(256) void repack_edges(const void* __restrict__ eraw, const int* __restrict__ mode,
                                                    int* __restrict__ out, int n2) {
    int i = blockIdx.x * 256 + threadIdx.x;
    if (i >= n2) return;
    int m = *mode;
    out[i] = m ? ((const int*)eraw)[i] : (int)((const long long*)eraw)[i];
}

// ---------------- degree / normalization ----------------
__global__ __launch_bounds__(256) void compute_deg(const int* __restrict__ dst, int* __restrict__ deg, int E) {
    int i = blockIdx.x * 256 + threadIdx.x;
    if (i < E) atomicAdd(&deg[dst[i]], 1);
}

__global__ __launch_bounds__(256) void compute_dinv(const int* __restrict__ deg, float* __restrict__ dinv, int N) {
    int i = blockIdx.x * 256 + threadIdx.x;
    if (i < N) dinv[i] = 1.0f / sqrtf((float)(deg[i] + 1));   // +1 self-loop
}

// ---------------- exclusive scan (rowptr) ----------------
__global__ __launch_bounds__(256) void scan_block(const int* __restrict__ deg, int* __restrict__ excl,
                                                  int* __restrict__ partials, int N) {
    __shared__ int s[256];
    int i = blockIdx.x * 256 + threadIdx.x;
    int v = (i < N) ? deg[i] : 0;
    s[threadIdx.x] = v;
    __syncthreads();
    for (int off = 1; off < 256; off <<= 1) {
        int t = (threadIdx.x >= off) ? s[threadIdx.x - off] : 0;
        __syncthreads();
        s[threadIdx.x] += t;
        __syncthreads();
    }
    if (i < N) excl[i] = s[threadIdx.x] - v;
    if (threadIdx.x == 255) partials[blockIdx.x] = s[255];
}

__global__ __launch_bounds__(256) void scan_partials(int* __restrict__ partials, int nb) {
    __shared__ int s[256];
    int v = (threadIdx.x < nb) ? partials[threadIdx.x] : 0;
    s[threadIdx.x] = v;
    __syncthreads();
    for (int off = 1; off < 256; off <<= 1) {
        int t = (threadIdx.x >= off) ? s[threadIdx.x - off] : 0;
        __syncthreads();
        s[threadIdx.x] += t;
        __syncthreads();
    }
    if (threadIdx.x < nb) partials[threadIdx.x] = s[threadIdx.x] - v;   // exclusive
}

__global__ __launch_bounds__(256) void add_offsets(int* __restrict__ excl, const int* __restrict__ partials, int N) {
    int i = blockIdx.x * 256 + threadIdx.x;
    if (i < N) excl[i] += partials[blockIdx.x];
}

// ---------------- CSR fill (counting sort by dst) ----------------
__global__ __launch_bounds__(256) void fill_csr(const int* __restrict__ src, const int* __restrict__ dst,
                                                const int* __restrict__ rowptr, int* __restrict__ cursor,
                                                int* __restrict__ csr_src, int E) {
    int e = blockIdx.x * 256 + threadIdx.x;
    if (e >= E) return;
    int d = dst[e];
    int pos = atomicAdd(&cursor[d], 1);
    csr_src[rowptr[d] + pos] = src[e];
}

// ---------------- fused gather + self-loop + bias + relu ----------------
// 32 lanes per node, float4 per lane. out[d] = relu(dinv[d]*sum(dinv[s]*t[s]) + dinv[d]^2*t[d] + b)
__global__ __launch_bounds__(256) void gather_nodes(const int* __restrict__ csr_src, const int* __restrict__ rowptr,
                                                    const float* __restrict__ dinv, const float* __restrict__ t,
                                                    const float* __restrict__ bias, float* __restrict__ out, int N, int E) {
    int idx = blockIdx.x * 256 + threadIdx.x;
    int node = idx >> 5;
    if (node >= N) return;
    int lane = idx & 31;
    int beg = rowptr[node];
    int end = (node + 1 < N) ? rowptr[node + 1] : E;
    float4 acc0 = make_float4(0.f, 0.f, 0.f, 0.f);
    float4 acc1 = make_float4(0.f, 0.f, 0.f, 0.f);
    int j = beg;
    for (; j + 1 < end; j += 2) {
        int s0 = csr_src[j], s1 = csr_src[j + 1];
        float w0 = dinv[s0], w1 = dinv[s1];
        float4 v0 = *((const float4*)(t + (size_t)s0 * D) + lane);
        float4 v1 = *((const float4*)(t + (size_t)s1 * D) + lane);
        acc0.x = fmaf(w0, v0.x, acc0.x); acc0.y = fmaf(w0, v0.y, acc0.y);
        acc0.z = fmaf(w0, v0.z, acc0.z); acc0.w = fmaf(w0, v0.w, acc0.w);
        acc1.x = fmaf(w1, v1.x, acc1.x); acc1.y = fmaf(w1, v1.y, acc1.y);
        acc1.z = fmaf(w1, v1.z, acc1.z); acc1.w = fmaf(w1, v1.w, acc1.w);
    }
    if (j < end) {
        int s0 = csr_src[j];
        float w0 = dinv[s0];
        float4 v0 = *((const float4*)(t + (size_t)s0 * D) + lane);
        acc0.x = fmaf(w0, v0.x, acc0.x); acc0.y = fmaf(w0, v0.y, acc0.y);
        acc0.z = fmaf(w0, v0.z, acc0.z); acc0.w = fmaf(w0, v0.w, acc0.w);
    }
    acc0.x += acc1.x; acc0.y += acc1.y; acc0.z += acc1.z; acc0.w += acc1.w;
    float di = dinv[node];
    float sn = di * di;
    float4 tv = *((const float4*)(t + (size_t)node * D) + lane);
    float4 b = ((const float4*)bias)[lane];
    float4 r;
    r.x = fmaxf(fmaf(di, acc0.x, fmaf(sn, tv.x, b.x)), 0.f);
    r.y = fmaxf(fmaf(di, acc0.y, fmaf(sn, tv.y, b.y)), 0.f);
    r.z = fmaxf(fmaf(di, acc0.z, fmaf(sn, tv.z, b.z)), 0.f);
    r.w = fmaxf(fmaf(di, acc0.w, fmaf(sn, tv.w, b.w)), 0.f);
    *((float4*)(out + (size_t)node * D) + lane) = r;
}

// ---------------- GEMM: C[N,128] = A[N,128] @ W[128,128] (+bias) ----------------
template<bool BIAS>
__global__ __launch_bounds__(256) void gemm128(const float* __restrict__ A, const float* __restrict__ W,
                                               const float* __restrict__ bias, float* __restrict__ C, int N) {
    __shared__ float Ws[64][D];
    __shared__ float As[32][D];
    int tid = threadIdx.x;
    int row0 = blockIdx.x * 32;
    for (int i = tid; i < 32 * 32; i += 256) {
        int r = i >> 5, c4 = i & 31;
        float4 v = make_float4(0.f, 0.f, 0.f, 0.f);
        if (row0 + r < N) v = *((const float4*)(A + (size_t)(row0 + r) * D) + c4);
        *((float4*)&As[r][0] + c4) = v;
    }
    int ct = tid & 31;
    int rt = tid >> 5;
    float acc[4][4] = {{0.f}};
    for (int kh = 0; kh < 2; kh++) {
        __syncthreads();
        for (int i = tid; i < 64 * 32; i += 256)
            ((float4*)Ws)[i] = ((const float4*)(W + kh * 64 * D))[i];
        __syncthreads();
        #pragma unroll
        for (int k = 0; k < 64; k += 4) {
            float4 w0 = *(const float4*)&Ws[k + 0][4 * ct];
            float4 w1 = *(const float4*)&Ws[k + 1][4 * ct];
            float4 w2 = *(const float4*)&Ws[k + 2][4 * ct];
            float4 w3 = *(const float4*)&Ws[k + 3][4 * ct];
            #pragma unroll
            for (int r = 0; r < 4; r++) {
                float4 av = *(const float4*)&As[rt * 4 + r][kh * 64 + k];
                acc[r][0] += av.x * w0.x + av.y * w1.x + av.z * w2.x + av.w * w3.x;
                acc[r][1] += av.x * w0.y + av.y * w1.y + av.z * w2.y + av.w * w3.y;
                acc[r][2] += av.x * w0.z + av.y * w1.z + av.z * w2.z + av.w * w3.z;
                acc[r][3] += av.x * w0.w + av.y * w1.w + av.z * w2.w + av.w * w3.w;
            }
        }
    }
    #pragma unroll
    for (int r = 0; r < 4; r++) {
        int row = row0 + rt * 4 + r;
        if (row < N) {
            float4 o = make_float4(acc[r][0], acc[r][1], acc[r][2], acc[r][3]);
            if (BIAS) {
                float4 b = *((const float4*)bias + ct);
                o.x += b.x; o.y += b.y; o.z += b.z; o.w += b.w;
            }
            *((float4*)(C + (size_t)row * D) + ct) = o;
        }
    }
}

// ---------------- post GEMM: C[N,40] = A[N,128] @ W[128,40] + bias ----------------
__global__ __launch_bounds__(256) void gemm_post(const float* __restrict__ A, const float* __restrict__ W,
                                                 const float* __restrict__ bias, float* __restrict__ C, int N) {
    __shared__ float WsT[40][132];
    __shared__ float As[32][132];
    int tid = threadIdx.x;
    for (int i = tid; i < 128 * 40; i += 256) {
        int k = i / 40, c = i % 40;
        WsT[c][k] = W[i];
    }
    int row0 = blockIdx.x * 32;
    for (int i = tid; i < 32 * 32; i += 256) {
        int r = i >> 5, c4 = i & 31;
        float4 v = make_float4(0.f, 0.f, 0.f, 0.f);
        if (row0 + r < N) v = *((const float4*)(A + (size_t)(row0 + r) * D) + c4);
        *((float4*)&As[r][0] + c4) = v;
    }
    __syncthreads();
    int r = tid >> 3;
    int cg = tid & 7;
    float acc[5] = {0.f, 0.f, 0.f, 0.f, 0.f};
    #pragma unroll
    for (int k = 0; k < 128; k += 4) {
        float4 av = *(const float4*)&As[r][k];
        #pragma unroll
        for (int j = 0; j < 5; j++) {
            float4 wv = *(const float4*)&WsT[cg * 5 + j][k];
            acc[j] += av.x * wv.x + av.y * wv.y + av.z * wv.z + av.w * wv.w;
        }
    }
    int row = row0 + r;
    if (row < N) {
        #pragma unroll
        for (int j = 0; j < 5; j++) {
            int c = cg * 5 + j;
            C[(size_t)row * 40 + c] = acc[j] + bias[c];
        }
    }
}

extern "C" void kernel_launch(void* const* d_in, const int* in_sizes, int n_in,
                              void* d_out, int out_size, void* d_ws, size_t ws_size,
                              hipStream_t stream) {
    const float* x      = (const float*)d_in[0];
    const void*  edges  = d_in[1];
    const float* W_pre  = (const float*)d_in[2];
    const float* b_pre  = (const float*)d_in[3];
    const float* W1     = (const float*)d_in[4];
    const float* b1     = (const float*)d_in[5];
    const float* W2     = (const float*)d_in[6];
    const float* b2     = (const float*)d_in[7];
    const float* W_post = (const float*)d_in[8];
    const float* b_post = (const float*)d_in[9];
    float* out = (float*)d_out;

    const int N = in_sizes[0] / D;      // 50000
    const int E = in_sizes[1] / 2;      // 800000

    // workspace layout
    char* ws = (char*)d_ws;
    size_t off = 0;
    auto alloc = [&](size_t bytes) { void* p = ws + off; off += (bytes + 255) & ~(size_t)255; return p; };
    float* bufA     = (float*)alloc((size_t)N * D * 4);
    float* bufB     = (float*)alloc((size_t)N * D * 4);
    float* dinv     = (float*)alloc((size_t)N * 4);
    int*   deg      = (int*)alloc((size_t)N * 4);
    int*   rowptr   = (int*)alloc((size_t)(N + 1) * 4);
    int*   cursor   = (int*)alloc((size_t)N * 4);
    int*   partials = (int*)alloc(1024);
    int*   mode     = (int*)alloc(256);
    int*   srcdst   = (int*)alloc((size_t)2 * E * 4);
    int*   csr_src  = (int*)alloc((size_t)E * 4);
    int* src = srcdst;
    int* dst = srcdst + E;

    const int nGemmBlocks = (N + 31) / 32;
    const int nScanBlocks = (N + 255) / 256;      // 196

    // graph prep (shared by both convs)
    hipMemsetAsync(deg, 0, (size_t)N * 4, stream);
    hipMemsetAsync(cursor, 0, (size_t)N * 4, stream);
    hipMemsetAsync(mode, 0, 4, stream);
    detect_mode<<<512, 256, 0, stream>>>((const int*)edges, mode, E);
    repack_edges<<<(2 * E + 255) / 256, 256, 0, stream>>>(edges, mode, srcdst, 2 * E);
    compute_deg<<<(E + 255) / 256, 256, 0, stream>>>(dst, deg, E);
    compute_dinv<<<(N + 255) / 256, 256, 0, stream>>>(deg, dinv, N);
    scan_block<<<nScanBlocks, 256, 0, stream>>>(deg, rowptr, partials, N);
    scan_partials<<<1, 256, 0, stream>>>(partials, nScanBlocks);
    add_offsets<<<nScanBlocks, 256, 0, stream>>>(rowptr, partials, N);
    fill_csr<<<(E + 255) / 256, 256, 0, stream>>>(src, dst, rowptr, cursor, csr_src, E);

    // pre MLP
    gemm128<true><<<nGemmBlocks, 256, 0, stream>>>(x, W_pre, b_pre, bufA, N);

    const int nGatherBlocks = (N * 32 + 255) / 256;

    // conv1
    gemm128<false><<<nGemmBlocks, 256, 0, stream>>>(bufA, W1, nullptr, bufB, N);
    gather_nodes<<<nGatherBlocks, 256, 0, stream>>>(csr_src, rowptr, dinv, bufB, b1, bufA, N, E);

    // conv2
    gemm128<false><<<nGemmBlocks, 256, 0, stream>>>(bufA, W2, nullptr, bufB, N);
    gather_nodes<<<nGatherBlocks, 256, 0, stream>>>(csr_src, rowptr, dinv, bufB, b2, bufA, N, E);

    // post MLP -> d_out
    gemm_post<<<nGemmBlocks, 256, 0, stream>>>(bufA, W_post, b_post, out, N);
}

// Round 5
// 366.731 us; speedup vs baseline: 8.1291x; 1.1952x over previous
//
#include <hip/hip_runtime.h>

#define D 128

typedef short bfrag __attribute__((ext_vector_type(8)));      // 8 bf16 = 4 VGPRs
typedef float f32x4 __attribute__((ext_vector_type(4)));
typedef unsigned short u16x4 __attribute__((ext_vector_type(4)));

// ---------------- bf16 split helpers ----------------
__device__ inline unsigned short bf16_rne(float x) {
    unsigned u = __float_as_uint(x);
    return (unsigned short)((u + 0x7FFFu + ((u >> 16) & 1u)) >> 16);
}
__device__ inline float bf16_to_f(unsigned short h) {
    return __uint_as_float(((unsigned)h) << 16);
}
// returns hi in bits [15:0], lo in bits [31:16]
__device__ inline unsigned split2p(float x) {
    unsigned short hi = bf16_rne(x);
    unsigned short lo = bf16_rne(x - bf16_to_f(hi));
    return (unsigned)hi | ((unsigned)lo << 16);
}

// ---------------- edge dtype detection + repack ----------------
__global__ __launch_bounds__(256) void detect_mode(const int* __restrict__ e, int* __restrict__ mode, int E) {
    int found = 0;
    for (int p = blockIdx.x * 256 + threadIdx.x; p < E; p += gridDim.x * 256)
        if (e[2 * p + 1] != 0) found = 1;
    if (found) atomicOr(mode, 1);   // 1 => int32, 0 => int64
}

__global__ __launch_bounds__(256) void repack_edges(const void* __restrict__ eraw, const int* __restrict__ mode,
                                                    int* __restrict__ out, int n2) {
    int i = blockIdx.x * 256 + threadIdx.x;
    if (i >= n2) return;
    int m = *mode;
    out[i] = m ? ((const int*)eraw)[i] : (int)((const long long*)eraw)[i];
}

// ---------------- degree / normalization ----------------
__global__ __launch_bounds__(256) void compute_deg(const int* __restrict__ dst, int* __restrict__ deg, int E) {
    int i = blockIdx.x * 256 + threadIdx.x;
    if (i < E) atomicAdd(&deg[dst[i]], 1);
}

__global__ __launch_bounds__(256) void compute_dinv(const int* __restrict__ deg, float* __restrict__ dinv, int N) {
    int i = blockIdx.x * 256 + threadIdx.x;
    if (i < N) dinv[i] = 1.0f / sqrtf((float)(deg[i] + 1));   // +1 self-loop
}

// ---------------- exclusive scan (rowptr) ----------------
__global__ __launch_bounds__(256) void scan_block(const int* __restrict__ deg, int* __restrict__ excl,
                                                  int* __restrict__ partials, int N) {
    __shared__ int s[256];
    int i = blockIdx.x * 256 + threadIdx.x;
    int v = (i < N) ? deg[i] : 0;
    s[threadIdx.x] = v;
    __syncthreads();
    for (int off = 1; off < 256; off <<= 1) {
        int t = (threadIdx.x >= off) ? s[threadIdx.x - off] : 0;
        __syncthreads();
        s[threadIdx.x] += t;
        __syncthreads();
    }
    if (i < N) excl[i] = s[threadIdx.x] - v;
    if (threadIdx.x == 255) partials[blockIdx.x] = s[255];
}

__global__ __launch_bounds__(256) void scan_partials(int* __restrict__ partials, int nb) {
    __shared__ int s[256];
    int v = (threadIdx.x < nb) ? partials[threadIdx.x] : 0;
    s[threadIdx.x] = v;
    __syncthreads();
    for (int off = 1; off < 256; off <<= 1) {
        int t = (threadIdx.x >= off) ? s[threadIdx.x - off] : 0;
        __syncthreads();
        s[threadIdx.x] += t;
        __syncthreads();
    }
    if (threadIdx.x < nb) partials[threadIdx.x] = s[threadIdx.x] - v;   // exclusive
}

__global__ __launch_bounds__(256) void add_offsets(int* __restrict__ excl, const int* __restrict__ partials, int N) {
    int i = blockIdx.x * 256 + threadIdx.x;
    if (i < N) excl[i] += partials[blockIdx.x];
}

// ---------------- CSR fill (counting sort by dst) ----------------
__global__ __launch_bounds__(256) void fill_csr(const int* __restrict__ src, const int* __restrict__ dst,
                                                const int* __restrict__ rowptr, int* __restrict__ cursor,
                                                int* __restrict__ csr_src, int E) {
    int e = blockIdx.x * 256 + threadIdx.x;
    if (e >= E) return;
    int d = dst[e];
    int pos = atomicAdd(&cursor[d], 1);
    csr_src[rowptr[d] + pos] = src[e];
}

// ---------------- fp32 -> bf16 hi/lo split (whole matrix) ----------------
__global__ __launch_bounds__(256) void split_matrix(const float* __restrict__ in, unsigned short* __restrict__ hi,
                                                    unsigned short* __restrict__ lo, int n4) {
    int i = blockIdx.x * 256 + threadIdx.x;
    if (i >= n4) return;
    float4 v = ((const float4*)in)[i];
    unsigned p0 = split2p(v.x), p1 = split2p(v.y), p2 = split2p(v.z), p3 = split2p(v.w);
    u16x4 h, l;
    h[0] = (unsigned short)p0; l[0] = (unsigned short)(p0 >> 16);
    h[1] = (unsigned short)p1; l[1] = (unsigned short)(p1 >> 16);
    h[2] = (unsigned short)p2; l[2] = (unsigned short)(p2 >> 16);
    h[3] = (unsigned short)p3; l[3] = (unsigned short)(p3 >> 16);
    ((u16x4*)hi)[i] = h;
    ((u16x4*)lo)[i] = l;
}

// ---------------- weight prep: transpose + split. wt[n][k] = W[k][n] (pad n) ----------------
__global__ __launch_bounds__(256) void prep_w(const float* __restrict__ W, unsigned short* __restrict__ wth,
                                              unsigned short* __restrict__ wtl, int K, int ncols, int nrows) {
    int i = blockIdx.x * 256 + threadIdx.x;
    if (i >= nrows * K) return;
    int n = i / K, k = i % K;
    float v = (n < ncols) ? W[k * ncols + n] : 0.f;
    unsigned p = split2p(v);
    wth[i] = (unsigned short)p;
    wtl[i] = (unsigned short)(p >> 16);
}

// ---------------- bf16x3 MFMA GEMM ----------------
// C[N, outW] = (Ahi+Alo) @ (Whi+Wlo), K=128.  One wave: 16-row strip x NTILES*16 cols.
// W fragments persist in VGPRs; waves grid-stride over strips.
// EPI=0: Cf fp32 [N][outW].  EPI=1: bias + split -> Chi/Clo bf16 pair [N][D].
// EPI=2: bias + fp32, mask col < outW (post layer).
template<int NTILES, int EPI>
__global__ __launch_bounds__(256) void gemm_mfma(const unsigned short* __restrict__ Ahi,
                                                 const unsigned short* __restrict__ Alo,
                                                 const unsigned short* __restrict__ Wth,
                                                 const unsigned short* __restrict__ Wtl,
                                                 const float* __restrict__ bias,
                                                 float* __restrict__ Cf,
                                                 unsigned short* __restrict__ Chi,
                                                 unsigned short* __restrict__ Clo,
                                                 int nStrips, int N, int outW) {
    int wave = threadIdx.x >> 6;
    int lane = threadIdx.x & 63;
    int l15 = lane & 15, lg = lane >> 4;
    int colbase = blockIdx.y * 64;

    // persistent B fragments: wt[col][k] contiguous in k -> 16B per lane
    bfrag wh[4][NTILES], wl[4][NTILES];
    #pragma unroll
    for (int ks = 0; ks < 4; ks++)
        #pragma unroll
        for (int nt = 0; nt < NTILES; nt++) {
            size_t off = (size_t)(colbase + nt * 16 + l15) * D + ks * 32 + lg * 8;
            wh[ks][nt] = *(const bfrag*)(Wth + off);
            wl[ks][nt] = *(const bfrag*)(Wtl + off);
        }

    for (int strip = blockIdx.x * 4 + wave; strip < nStrips; strip += gridDim.x * 4) {
        int row0 = strip * 16;
        bfrag ah[4], al[4];
        #pragma unroll
        for (int ks = 0; ks < 4; ks++) {
            size_t off = (size_t)(row0 + l15) * D + ks * 32 + lg * 8;
            ah[ks] = *(const bfrag*)(Ahi + off);
            al[ks] = *(const bfrag*)(Alo + off);
        }
        f32x4 acc[NTILES];
        #pragma unroll
        for (int nt = 0; nt < NTILES; nt++) acc[nt] = (f32x4){0.f, 0.f, 0.f, 0.f};
        #pragma unroll
        for (int ks = 0; ks < 4; ks++) {
            #pragma unroll
            for (int nt = 0; nt < NTILES; nt++)
                acc[nt] = __builtin_amdgcn_mfma_f32_16x16x32_bf16(ah[ks], wh[ks][nt], acc[nt], 0, 0, 0);
            #pragma unroll
            for (int nt = 0; nt < NTILES; nt++)
                acc[nt] = __builtin_amdgcn_mfma_f32_16x16x32_bf16(ah[ks], wl[ks][nt], acc[nt], 0, 0, 0);
            #pragma unroll
            for (int nt = 0; nt < NTILES; nt++)
                acc[nt] = __builtin_amdgcn_mfma_f32_16x16x32_bf16(al[ks], wh[ks][nt], acc[nt], 0, 0, 0);
        }
        // C/D layout (m89-verified): col = lane&15, row = (lane>>4)*4 + reg
        #pragma unroll
        for (int nt = 0; nt < NTILES; nt++) {
            int col = colbase + nt * 16 + l15;
            #pragma unroll
            for (int r = 0; r < 4; r++) {
                int row = row0 + lg * 4 + r;
                if (row >= N) continue;
                float v = acc[nt][r];
                if (EPI == 0) {
                    Cf[(size_t)row * outW + col] = v;
                } else if (EPI == 1) {
                    v += bias[col];
                    unsigned p = split2p(v);
                    Chi[(size_t)row * D + col] = (unsigned short)p;
                    Clo[(size_t)row * D + col] = (unsigned short)(p >> 16);
                } else {
                    if (col < outW) Cf[(size_t)row * outW + col] = v + bias[col];
                }
            }
        }
    }
}

// ---------------- fused gather + self-loop + bias + relu -> bf16 hi/lo pair ----------------
__global__ __launch_bounds__(256) void gather_nodes(const int* __restrict__ csr_src, const int* __restrict__ rowptr,
                                                    const float* __restrict__ dinv, const float* __restrict__ t,
                                                    const float* __restrict__ bias,
                                                    unsigned short* __restrict__ outHi, unsigned short* __restrict__ outLo,
                                                    int N, int E) {
    int idx = blockIdx.x * 256 + threadIdx.x;
    int node = idx >> 5;
    if (node >= N) return;
    int lane = idx & 31;
    int beg = rowptr[node];
    int end = (node + 1 < N) ? rowptr[node + 1] : E;
    float4 acc0 = make_float4(0.f, 0.f, 0.f, 0.f);
    float4 acc1 = make_float4(0.f, 0.f, 0.f, 0.f);
    int j = beg;
    for (; j + 1 < end; j += 2) {
        int s0 = csr_src[j], s1 = csr_src[j + 1];
        float w0 = dinv[s0], w1 = dinv[s1];
        float4 v0 = *((const float4*)(t + (size_t)s0 * D) + lane);
        float4 v1 = *((const float4*)(t + (size_t)s1 * D) + lane);
        acc0.x = fmaf(w0, v0.x, acc0.x); acc0.y = fmaf(w0, v0.y, acc0.y);
        acc0.z = fmaf(w0, v0.z, acc0.z); acc0.w = fmaf(w0, v0.w, acc0.w);
        acc1.x = fmaf(w1, v1.x, acc1.x); acc1.y = fmaf(w1, v1.y, acc1.y);
        acc1.z = fmaf(w1, v1.z, acc1.z); acc1.w = fmaf(w1, v1.w, acc1.w);
    }
    if (j < end) {
        int s0 = csr_src[j];
        float w0 = dinv[s0];
        float4 v0 = *((const float4*)(t + (size_t)s0 * D) + lane);
        acc0.x = fmaf(w0, v0.x, acc0.x); acc0.y = fmaf(w0, v0.y, acc0.y);
        acc0.z = fmaf(w0, v0.z, acc0.z); acc0.w = fmaf(w0, v0.w, acc0.w);
    }
    acc0.x += acc1.x; acc0.y += acc1.y; acc0.z += acc1.z; acc0.w += acc1.w;
    float di = dinv[node];
    float sn = di * di;
    float4 tv = *((const float4*)(t + (size_t)node * D) + lane);
    float4 b = ((const float4*)bias)[lane];
    float4 r;
    r.x = fmaxf(fmaf(di, acc0.x, fmaf(sn, tv.x, b.x)), 0.f);
    r.y = fmaxf(fmaf(di, acc0.y, fmaf(sn, tv.y, b.y)), 0.f);
    r.z = fmaxf(fmaf(di, acc0.z, fmaf(sn, tv.z, b.z)), 0.f);
    r.w = fmaxf(fmaf(di, acc0.w, fmaf(sn, tv.w, b.w)), 0.f);
    unsigned p0 = split2p(r.x), p1 = split2p(r.y), p2 = split2p(r.z), p3 = split2p(r.w);
    u16x4 h, l;
    h[0] = (unsigned short)p0; l[0] = (unsigned short)(p0 >> 16);
    h[1] = (unsigned short)p1; l[1] = (unsigned short)(p1 >> 16);
    h[2] = (unsigned short)p2; l[2] = (unsigned short)(p2 >> 16);
    h[3] = (unsigned short)p3; l[3] = (unsigned short)(p3 >> 16);
    ((u16x4*)(outHi + (size_t)node * D))[lane] = h;
    ((u16x4*)(outLo + (size_t)node * D))[lane] = l;
}

extern "C" void kernel_launch(void* const* d_in, const int* in_sizes, int n_in,
                              void* d_out, int out_size, void* d_ws, size_t ws_size,
                              hipStream_t stream) {
    const float* x      = (const float*)d_in[0];
    const void*  edges  = d_in[1];
    const float* W_pre  = (const float*)d_in[2];
    const float* b_pre  = (const float*)d_in[3];
    const float* W1     = (const float*)d_in[4];
    const float* b1     = (const float*)d_in[5];
    const float* W2     = (const float*)d_in[6];
    const float* b2     = (const float*)d_in[7];
    const float* W_post = (const float*)d_in[8];
    const float* b_post = (const float*)d_in[9];
    float* out = (float*)d_out;

    const int N = in_sizes[0] / D;        // 50000
    const int E = in_sizes[1] / 2;        // 800000
    const int nStrips = (N + 15) / 16;    // 3125
    const int Npad = nStrips * 16;

    // ---- workspace layout (persistent buffers) ----
    char* ws = (char*)d_ws;
    size_t off = 0;
    auto alloc = [&](size_t bytes) { void* p = ws + off; off += (bytes + 255) & ~(size_t)255; return p; };
    unsigned short* pAhi = (unsigned short*)alloc((size_t)Npad * D * 2);
    unsigned short* pAlo = (unsigned short*)alloc((size_t)Npad * D * 2);
    unsigned short* pBhi = (unsigned short*)alloc((size_t)Npad * D * 2);
    unsigned short* pBlo = (unsigned short*)alloc((size_t)Npad * D * 2);
    float*          bufT = (float*)alloc((size_t)Npad * D * 4);
    float* dinv     = (float*)alloc((size_t)N * 4);
    int*   rowptr   = (int*)alloc((size_t)(N + 1) * 4);
    int*   csr_src  = (int*)alloc((size_t)E * 4);
    unsigned short* wpre_h  = (unsigned short*)alloc(128 * 128 * 2);
    unsigned short* wpre_l  = (unsigned short*)alloc(128 * 128 * 2);
    unsigned short* w1_h    = (unsigned short*)alloc(128 * 128 * 2);
    unsigned short* w1_l    = (unsigned short*)alloc(128 * 128 * 2);
    unsigned short* w2_h    = (unsigned short*)alloc(128 * 128 * 2);
    unsigned short* w2_l    = (unsigned short*)alloc(128 * 128 * 2);
    unsigned short* wpost_h = (unsigned short*)alloc(48 * 128 * 2);
    unsigned short* wpost_l = (unsigned short*)alloc(48 * 128 * 2);

    // ---- prep-phase temporaries OVERLAY bufT (all dead before first bufT write) ----
    {
        char* t = (char*)bufT;
        size_t toff = 0;
        auto talloc = [&](size_t bytes) { void* p = t + toff; toff += (bytes + 255) & ~(size_t)255; return p; };
        int* srcdst   = (int*)talloc((size_t)2 * E * 4);   // 6.4 MB
        int* deg      = (int*)talloc((size_t)N * 4);
        int* cursor   = (int*)talloc((size_t)N * 4);
        int* partials = (int*)talloc(1024);
        int* mode     = (int*)talloc(256);
        int* src = srcdst;
        int* dst = srcdst + E;

        const int nScanBlocks = (N + 255) / 256;

        (void)hipMemsetAsync(deg, 0, (size_t)N * 4, stream);
        (void)hipMemsetAsync(cursor, 0, (size_t)N * 4, stream);
        (void)hipMemsetAsync(mode, 0, 4, stream);
        detect_mode<<<512, 256, 0, stream>>>((const int*)edges, mode, E);
        repack_edges<<<(2 * E + 255) / 256, 256, 0, stream>>>(edges, mode, srcdst, 2 * E);
        compute_deg<<<(E + 255) / 256, 256, 0, stream>>>(dst, deg, E);
        compute_dinv<<<(N + 255) / 256, 256, 0, stream>>>(deg, dinv, N);
        scan_block<<<nScanBlocks, 256, 0, stream>>>(deg, rowptr, partials, N);
        scan_partials<<<1, 256, 0, stream>>>(partials, nScanBlocks);
        add_offsets<<<nScanBlocks, 256, 0, stream>>>(rowptr, partials, N);
        fill_csr<<<(E + 255) / 256, 256, 0, stream>>>(src, dst, rowptr, cursor, csr_src, E);
    }

    // weight transpose+split (tiny)
    prep_w<<<(128 * 128 + 255) / 256, 256, 0, stream>>>(W_pre, wpre_h, wpre_l, 128, 128, 128);
    prep_w<<<(128 * 128 + 255) / 256, 256, 0, stream>>>(W1, w1_h, w1_l, 128, 128, 128);
    prep_w<<<(128 * 128 + 255) / 256, 256, 0, stream>>>(W2, w2_h, w2_l, 128, 128, 128);
    prep_w<<<(48 * 128 + 255) / 256, 256, 0, stream>>>(W_post, wpost_h, wpost_l, 128, 40, 48);

    // x -> hi/lo pair
    split_matrix<<<(N * D / 4 + 255) / 256, 256, 0, stream>>>(x, pAhi, pAlo, N * D / 4);

    const int nGatherBlocks = (N * 32 + 255) / 256;
    dim3 g128(256, 2);   // 2048 waves, 2 column-halves

    // pre MLP: h1(pair B) = x @ W_pre + b_pre
    gemm_mfma<4, 1><<<g128, 256, 0, stream>>>(pAhi, pAlo, wpre_h, wpre_l, b_pre, nullptr, pBhi, pBlo, nStrips, N, D);

    // conv1: t = h1 @ W1 ; h2(pair A) = relu(gather(t) + b1)
    gemm_mfma<4, 0><<<g128, 256, 0, stream>>>(pBhi, pBlo, w1_h, w1_l, nullptr, bufT, nullptr, nullptr, nStrips, N, D);
    gather_nodes<<<nGatherBlocks, 256, 0, stream>>>(csr_src, rowptr, dinv, bufT, b1, pAhi, pAlo, N, E);

    // conv2: t = h2 @ W2 ; h3(pair B) = relu(gather(t) + b2)
    gemm_mfma<4, 0><<<g128, 256, 0, stream>>>(pAhi, pAlo, w2_h, w2_l, nullptr, bufT, nullptr, nullptr, nStrips, N, D);
    gather_nodes<<<nGatherBlocks, 256, 0, stream>>>(csr_src, rowptr, dinv, bufT, b2, pBhi, pBlo, N, E);

    // post MLP: out = h3 @ W_post + b_post  (40 cols, padded to 48)
    gemm_mfma<3, 2><<<dim3(256, 1), 256, 0, stream>>>(pBhi, pBlo, wpost_h, wpost_l, b_post, out, nullptr, nullptr, nStrips, N, 40);
}